// Round 10
// baseline (437.304 us; speedup 1.0000x reference)
//
#include <hip/hip_runtime.h>
#include <hip/hip_bf16.h>
#include <float.h>

#define BB 64
#define NN 900
#define CC 91
#define MM 128
#define BIG 1e18
#define DINF __builtin_huge_val()
#define NSLOT 15              // 15*64 = 960 >= 900 columns per lane-slot grid
#define LAST_VALID 4          // slot 14 valid for lanes 0..3 (896+lane < 900)
#define TPB_C 128

// ---------------------------------------------------------------------------
// Kernel 1a: per-pred softmax stats (mx, ssum), sequential reduction order
// identical to the passing cost_kernel. Writes float2 [mx,ssum] per pred.
// ---------------------------------------------------------------------------
__global__ __launch_bounds__(TPB_C) void stats_kernel(
    const float* __restrict__ logits,   // [B,N,C]
    float* __restrict__ stats)          // [B,N,2]
{
    const int b   = blockIdx.y;
    const int p0  = blockIdx.x * TPB_C;
    const int cnt = min(TPB_C, NN - p0);
    const int tid = threadIdx.x;

    __shared__ float s_lg[TPB_C * CC];   // 46592 B

    {
        const float* gbase = logits + ((size_t)b * NN + p0) * CC;
        const int total = cnt * CC;
        const int n4 = total >> 2;
        for (int k = tid; k < n4; k += TPB_C)
            ((float4*)s_lg)[k] = ((const float4*)gbase)[k];
        for (int k = (n4 << 2) + tid; k < total; k += TPB_C)
            s_lg[k] = gbase[k];
    }
    __syncthreads();
    if (tid >= cnt) return;

    const float* lg = s_lg + tid * CC;
    float mx = -INFINITY;
    for (int c = 0; c < CC; ++c) mx = fmaxf(mx, lg[c]);
    float ssum = 0.f;
    for (int c = 0; c < CC; ++c) ssum += expf(lg[c] - mx);

    ((float2*)stats)[(size_t)b * NN + p0 + tid] = make_float2(mx, ssum);
}

// ---------------------------------------------------------------------------
// Kernel 1b: cost fill. One block per (b, j) target pair; thread t computes
// 4 adjacent preds -> one coalesced float4 store. 8192 blocks x 4 waves =
// deep TLP (vs old kernel's 1 wave/SIMD). Expression tree identical to the
// passing cost_kernel.
// ---------------------------------------------------------------------------
__global__ __launch_bounds__(256) void fill_kernel(
    const float* __restrict__ boxes,    // [B,N,4]
    const int*   __restrict__ tlabels,  // [B,M]
    const float* __restrict__ tboxes,   // [B,M,4]
    const float* __restrict__ stats,    // [B,N,2]
    const float* __restrict__ logits,   // [B,N,C]
    float* __restrict__ costT)          // [B,M,N]
{
    const int j = blockIdx.x;           // target index
    const int b = blockIdx.y;
    const int t = threadIdx.x;
    if (t >= NN / 4) return;            // 225 active threads
    const int p4 = t * 4;

    const int    tl = tlabels[b * MM + j];
    const float4 tb = ((const float4*)tboxes)[(size_t)b * MM + j];
    const float tcx = tb.x, tcy = tb.y, tw = tb.z, th = tb.w;
    const float tx0 = tcx - 0.5f * tw, ty0 = tcy - 0.5f * th;
    const float tx1 = tcx + 0.5f * tw, ty1 = tcy + 0.5f * th;
    const float tarea = (tx1 - tx0) * (ty1 - ty0);

    const float4* bx4 = (const float4*)boxes + (size_t)b * NN + p4;
    const float4  s01 = ((const float4*)stats)[((size_t)b * NN + p4) >> 1];
    const float4  s23 = ((const float4*)stats)[(((size_t)b * NN + p4) >> 1) + 1];
    const float   smx[4] = {s01.x, s01.z, s23.x, s23.z};
    const float   ssm[4] = {s01.y, s01.w, s23.y, s23.w};

    float res[4];
    #pragma unroll
    for (int k = 0; k < 4; ++k) {
        const float4 bx = bx4[k];
        const float cx = bx.x, cy = bx.y, w = bx.z, h = bx.w;
        const float px0 = cx - 0.5f * w, py0 = cy - 0.5f * h;
        const float px1 = cx + 0.5f * w, py1 = cy + 0.5f * h;
        const float parea = (px1 - px0) * (py1 - py0);

        float l1 = ((fabsf(cx - tcx) + fabsf(cy - tcy)) + fabsf(w - tw)) + fabsf(h - th);
        float iw = fminf(px1, tx1) - fmaxf(px0, tx0); iw = fmaxf(iw, 0.f);
        float ih = fminf(py1, ty1) - fmaxf(py0, ty0); ih = fmaxf(ih, 0.f);
        const float inter = iw * ih;
        const float uni   = parea + tarea - inter;
        const float iou   = inter / (uni + 1e-6f);
        const float enc   = (fmaxf(px1, tx1) - fminf(px0, tx0)) *
                            (fmaxf(py1, ty1) - fminf(py0, ty0)) + 1e-6f;
        const float giou  = iou - (enc - uni) / enc;

        const float lgt  = logits[((size_t)b * NN + p4 + k) * CC + tl];
        const float pcls = expf(lgt - smx[k]) / ssm[k];
        res[k] = (1.0f * (-pcls) + 5.0f * l1) + 2.0f * (-giou);
    }
    ((float4*)(costT + (size_t)(b * MM + j) * NN))[t] =
        make_float4(res[0], res[1], res[2], res[3]);
}

// ---------------------------------------------------------------------------
// Fallback: round-3 monolithic cost kernel (used only if ws too small).
// ---------------------------------------------------------------------------
__global__ __launch_bounds__(TPB_C) void cost_kernel(
    const float* __restrict__ logits, const float* __restrict__ boxes,
    const int* __restrict__ tlabels, const float* __restrict__ tboxes,
    float* __restrict__ costT)
{
    const int b   = blockIdx.y;
    const int p0  = blockIdx.x * TPB_C;
    const int cnt = min(TPB_C, NN - p0);
    const int tid = threadIdx.x;

    __shared__ float s_lg[TPB_C * CC];
    __shared__ float s_tb[MM][4];
    __shared__ int   s_tl[MM];

    {
        s_tl[tid] = tlabels[b * MM + tid];
        const float4 tb4 = ((const float4*)tboxes)[(size_t)b * MM + tid];
        s_tb[tid][0] = tb4.x; s_tb[tid][1] = tb4.y;
        s_tb[tid][2] = tb4.z; s_tb[tid][3] = tb4.w;
    }
    {
        const float* gbase = logits + ((size_t)b * NN + p0) * CC;
        const int total = cnt * CC;
        const int n4 = total >> 2;
        for (int k = tid; k < n4; k += TPB_C)
            ((float4*)s_lg)[k] = ((const float4*)gbase)[k];
        for (int k = (n4 << 2) + tid; k < total; k += TPB_C)
            s_lg[k] = gbase[k];
    }
    __syncthreads();
    if (tid >= cnt) return;

    const float* lg = s_lg + tid * CC;
    float mx = -INFINITY;
    for (int c = 0; c < CC; ++c) mx = fmaxf(mx, lg[c]);
    float ssum = 0.f;
    for (int c = 0; c < CC; ++c) ssum += expf(lg[c] - mx);

    const float4 bx4 = ((const float4*)boxes)[(size_t)b * NN + p0 + tid];
    const float cx = bx4.x, cy = bx4.y, w = bx4.z, h = bx4.w;
    const float px0 = cx - 0.5f * w, py0 = cy - 0.5f * h;
    const float px1 = cx + 0.5f * w, py1 = cy + 0.5f * h;
    const float parea = (px1 - px0) * (py1 - py0);

    float* outp = costT + (size_t)b * MM * NN + p0 + tid;
    for (int j = 0; j < MM; ++j) {
        const float tcx = s_tb[j][0], tcy = s_tb[j][1], tw = s_tb[j][2], th = s_tb[j][3];
        float l1 = ((fabsf(cx - tcx) + fabsf(cy - tcy)) + fabsf(w - tw)) + fabsf(h - th);
        const float tx0 = tcx - 0.5f * tw, ty0 = tcy - 0.5f * th;
        const float tx1 = tcx + 0.5f * tw, ty1 = tcy + 0.5f * th;
        float iw = fminf(px1, tx1) - fmaxf(px0, tx0); iw = fmaxf(iw, 0.f);
        float ih = fminf(py1, ty1) - fmaxf(py0, ty0); ih = fmaxf(ih, 0.f);
        const float inter = iw * ih;
        const float tarea = (tx1 - tx0) * (ty1 - ty0);
        const float uni   = parea + tarea - inter;
        const float iou   = inter / (uni + 1e-6f);
        const float enc   = (fmaxf(px1, tx1) - fminf(px0, tx0)) *
                            (fmaxf(py1, ty1) - fminf(py0, ty0)) + 1e-6f;
        const float giou  = iou - (enc - uni) / enc;
        const float pcls  = expf(lg[s_tl[j]] - mx) / ssum;
        const float cost  = (1.0f * (-pcls) + 5.0f * l1) + 2.0f * (-giou);
        outp[(size_t)j * NN] = cost;
    }
}

// ---------------------------------------------------------------------------
// DPP helpers (literal-constant template args; min lands in lane 63).
// ---------------------------------------------------------------------------
template<int CTRL, int ROW_MASK>
__device__ __forceinline__ unsigned dpp_min_u32_step(unsigned x) {
    const unsigned m = (unsigned)__builtin_amdgcn_update_dpp((int)x, (int)x, CTRL, ROW_MASK, 0xF, false);
    return m < x ? m : x;
}
__device__ __forceinline__ unsigned wave_min_u32(unsigned x) {
    x = dpp_min_u32_step<0xB1,  0xF>(x);  // quad_perm xor1
    x = dpp_min_u32_step<0x4E,  0xF>(x);  // quad_perm xor2
    x = dpp_min_u32_step<0x141, 0xF>(x);  // row_half_mirror
    x = dpp_min_u32_step<0x140, 0xF>(x);  // row_mirror
    x = dpp_min_u32_step<0x142, 0xA>(x);  // row_bcast15 -> rows 1,3
    x = dpp_min_u32_step<0x143, 0xC>(x);  // row_bcast31 -> rows 2,3
    return (unsigned)__builtin_amdgcn_readlane((int)x, 63);
}
__device__ __forceinline__ int d_hi(double d) { return (int)(__double_as_longlong(d) >> 32); }
__device__ __forceinline__ int d_lo(double d) { return (int)__double_as_longlong(d); }
__device__ __forceinline__ double mk_d(int hi, int lo) {
    return __longlong_as_double(((long long)hi << 32) | (unsigned long long)(unsigned)lo);
}

// ---------------------------------------------------------------------------
// Kernel 2: JV LSA, one wave per batch. UNCHANGED from round-9 (313 us,
// absmax 0) to isolate the cost-path experiment.
// ---------------------------------------------------------------------------
__global__ __launch_bounds__(64) void lsa_kernel(
    const float* __restrict__ costT,  // [B,M,N]
    int* __restrict__ out)            // rows [B,M] then cols [B,M], int32
{
    const int b    = blockIdx.x;
    const int lane = threadIdx.x;

    __shared__ double s_u[MM + 1];
    __shared__ int    s_p[NN + 1];
    __shared__ int    s_c4r[MM];
    __shared__ int    s_spill[3 * (NN + 2)];   // pathological path spill

    double v[NSLOT], minv[NSLOT];
    unsigned pay[NSLOT], pay_base[NSLOT];
    float  cv[NSLOT];

    for (int j = lane; j <= NN; j += 64) s_p[j] = 0;
    for (int i = lane; i <= MM; i += 64) s_u[i] = 0.0;
    #pragma unroll
    for (int s = 0; s < NSLOT; ++s) {
        v[s] = 0.0;
        pay_base[s] = ((unsigned)(s * 64 + lane + 1) << 18);  // p=0 initially
        pay[s] = pay_base[s];
    }
    __syncthreads();

    const float* cb = costT + (size_t)b * MM * NN;

    // prefetch row 0 (Dijkstra i=1)
    #pragma unroll
    for (int s = 0; s < NSLOT; ++s) {
        const bool valid = (s < NSLOT - 1) || (lane < LAST_VALID);
        cv[s] = valid ? cb[s * 64 + lane] : 0.f;
    }

    for (int i = 1; i <= MM; ++i) {
        unsigned used_mask = 0;
        #pragma unroll
        for (int s = 0; s < NSLOT; ++s) minv[s] = BIG;

        int T = 0;
        int curj0 = 0;
        int curi0 = i;
        int curway = 0;
        int nspill = 0;
        double ui0 = 0.0;
        int my_j0 = -1, my_i0 = 0, my_way = 0;

        while (true) {
            if (T < 63) {
                if (lane == T) { my_j0 = curj0; my_i0 = curi0; my_way = curway; }
            } else {
                if (lane == 0) {
                    s_spill[3 * nspill]     = curj0;
                    s_spill[3 * nspill + 1] = curi0;
                    s_spill[3 * nspill + 2] = curway;
                }
                ++nspill;
            }
            if (curj0 > 0) {
                const int jp = curj0 - 1;
                if ((jp & 63) == lane) used_mask |= 1u << (jp >> 6);
            }

            // ---- scan: fr-guarded improvement of (minv, payload)
            const unsigned pay_or = (unsigned)curj0 << 8;
            #pragma unroll
            for (int s = 0; s < NSLOT; ++s) {
                const bool valid = (s < NSLOT - 1) || (lane < LAST_VALID);
                const bool fr = valid && !((used_mask >> s) & 1u);
                const double cur = ((double)cv[s] - ui0) - v[s];
                const bool imp = fr && (cur < minv[s]);
                if (imp) { minv[s] = cur; pay[s] = pay_base[s] | pay_or; }
            }

            // ---- per-lane tournament tree (depth 4), left wins ties
            double n1v[8]; unsigned n1p[8];
            #pragma unroll
            for (int s = 0; s < 8; ++s) {
                const int a = 2 * s, c = 2 * s + 1;
                double va = minv[a]; unsigned pa = pay[a];
                if (c < NSLOT) { if (minv[c] < va) { va = minv[c]; pa = pay[c]; } }
                n1v[s] = va; n1p[s] = pa;
            }
            double n2v[4]; unsigned n2p[4];
            #pragma unroll
            for (int s = 0; s < 4; ++s) {
                double va = n1v[2*s]; unsigned pa = n1p[2*s];
                if (n1v[2*s+1] < va) { va = n1v[2*s+1]; pa = n1p[2*s+1]; }
                n2v[s] = va; n2p[s] = pa;
            }
            double n3v[2]; unsigned n3p[2];
            #pragma unroll
            for (int s = 0; s < 2; ++s) {
                double va = n2v[2*s]; unsigned pa = n2p[2*s];
                if (n2v[2*s+1] < va) { va = n2v[2*s+1]; pa = n2p[2*s+1]; }
                n3v[s] = va; n3p[s] = pa;
            }
            double bv = n3v[0]; unsigned bpay = n3p[0];
            if (n3v[1] < bv) { bv = n3v[1]; bpay = n3p[1]; }

            // ---- cross-lane argmin: hi-word DPP fast path
            const double bvn = bv + 0.0;
            const int hi = d_hi(bvn);
            const int sm = hi >> 31;
            const unsigned th = (unsigned)(hi ^ (sm | 0x80000000));
            const unsigned minhi = wave_min_u32(th);

            const unsigned long long hit = __ballot(th == minhi);
            unsigned wpay; double delta;
            if (__builtin_popcountll(hit) == 1) {
                const int src = (int)__builtin_ctzll(hit);
                wpay  = (unsigned)__builtin_amdgcn_readlane((int)bpay, src);
                delta = mk_d(__builtin_amdgcn_readlane(hi, src),
                             __builtin_amdgcn_readlane(d_lo(bvn), src));
            } else {
                const unsigned tl = (unsigned)(d_lo(bvn) ^ sm);
                const unsigned minlo = wave_min_u32((th == minhi) ? tl : 0xFFFFFFFFu);
                const bool full = (th == minhi) && (tl == minlo);
                wpay = wave_min_u32(full ? bpay : 0xFFFFFFFFu);
                const int src = (int)__builtin_ctzll(__ballot(full));
                delta = mk_d(__builtin_amdgcn_readlane(hi, src),
                             __builtin_amdgcn_readlane(d_lo(bvn), src));
            }
            const int j1   = (int)(wpay >> 18);
            const int way1 = (int)((wpay >> 8) & 0x3FF);
            const int pj1  = (int)(wpay & 0xFF);

            // issue next-row loads ASAP
            double ui_next = 0.0;
            if (pj1 != 0) {
                const float* crow = cb + (size_t)(pj1 - 1) * NN;
                #pragma unroll
                for (int s = 0; s < NSLOT; ++s) {
                    const bool valid = (s < NSLOT - 1) || (lane < LAST_VALID);
                    if (valid) cv[s] = crow[s * 64 + lane];
                }
                ui_next = s_u[pj1];
            }

            // ---- u-updates
            if (T < 63) {
                if (lane <= T) s_u[my_i0] += delta;
            } else {
                if (lane == 0) s_u[i] += delta;
                double uval[NSLOT];
                #pragma unroll
                for (int s = 0; s < NSLOT; ++s) {
                    const bool valid = (s < NSLOT - 1) || (lane < LAST_VALID);
                    if (valid && ((used_mask >> s) & 1u))
                        uval[s] = s_u[pay_base[s] & 0xFF];
                }
                #pragma unroll
                for (int s = 0; s < NSLOT; ++s) {
                    const bool valid = (s < NSLOT - 1) || (lane < LAST_VALID);
                    if (valid && ((used_mask >> s) & 1u))
                        s_u[pay_base[s] & 0xFF] = uval[s] + delta;
                }
            }
            // ---- v / minv updates
            #pragma unroll
            for (int s = 0; s < NSLOT; ++s) {
                const bool valid = (s < NSLOT - 1) || (lane < LAST_VALID);
                if (valid) {
                    const bool ub = (used_mask >> s) & 1u;
                    v[s]    = ub ? v[s] - delta : v[s];
                    minv[s] = ub ? DINF : minv[s] - delta;
                }
            }

            if (pj1 == 0) {
                // ---- augment via register chase
                int ja = j1, jb = way1;
                const int cap = (T < 63) ? T : 62;
                while (jb != 0) {
                    int np, nw;
                    const unsigned long long bal = __ballot(lane <= cap && my_j0 == jb);
                    if (bal != 0) {
                        const int src = (int)__builtin_ctzll(bal);
                        np = __builtin_amdgcn_readlane(my_i0, src);
                        nw = __builtin_amdgcn_readlane(my_way, src);
                    } else {
                        np = 0; nw = 0;
                        for (int k = 0; k < nspill; ++k) {
                            if (s_spill[3 * k] == jb) {
                                np = s_spill[3 * k + 1];
                                nw = s_spill[3 * k + 2];
                                break;
                            }
                        }
                    }
                    if (lane == 0) s_p[ja] = np;
                    ja = jb; jb = nw;
                }
                if (lane == 0) s_p[ja] = i;
                break;
            }
            curj0 = j1; curi0 = pj1; curway = way1; ui0 = ui_next; ++T;
        }

        // refresh cached p[j] (payload base) for this lane's columns
        #pragma unroll
        for (int s = 0; s < NSLOT; ++s) {
            const bool valid = (s < NSLOT - 1) || (lane < LAST_VALID);
            if (valid) {
                const int j = s * 64 + lane + 1;
                pay_base[s] = ((unsigned)j << 18) | (unsigned)s_p[j];
            }
        }
        // prefetch first row of next Dijkstra
        if (i < MM) {
            const float* crow = cb + (size_t)i * NN;
            #pragma unroll
            for (int s = 0; s < NSLOT; ++s) {
                const bool valid = (s < NSLOT - 1) || (lane < LAST_VALID);
                if (valid) cv[s] = crow[s * 64 + lane];
            }
        }
    }

    // col4row: target t -> matched pred index
    for (int j = 1 + lane; j <= NN; j += 64) {
        const int pj = s_p[j];
        if (pj > 0) s_c4r[pj - 1] = j - 1;
    }
    __syncthreads();

    // transposed return: rows = sorted pred indices, cols = target permutation
    for (int t = lane; t < MM; t += 64) {
        const int val = s_c4r[t];
        int rank = 0;
        for (int q = 0; q < MM; ++q) rank += (s_c4r[q] < val);
        out[(size_t)b * MM + rank] = val;
        out[(size_t)BB * MM + (size_t)b * MM + rank] = t;
    }
}

extern "C" void kernel_launch(void* const* d_in, const int* in_sizes, int n_in,
                              void* d_out, int out_size, void* d_ws, size_t ws_size,
                              hipStream_t stream) {
    const float* logits  = (const float*)d_in[0];   // [64,900,91] f32
    const float* boxes   = (const float*)d_in[1];   // [64,900,4]  f32
    const int*   tlabels = (const int*)d_in[2];     // [64,128]    i32 (from i64)
    const float* tboxes  = (const float*)d_in[3];   // [64,128,4]  f32
    int*   out   = (int*)d_out;                     // rows[64,128] ++ cols[64,128]
    float* costT = (float*)d_ws;                    // [64,128,900] f32 = 29.49 MB

    const size_t costT_bytes = (size_t)BB * MM * NN * 4;
    const size_t stats_bytes = (size_t)BB * NN * 2 * 4;

    if (ws_size >= costT_bytes + stats_bytes) {
        float* stats = (float*)((char*)d_ws + costT_bytes);   // [64,900,2]
        dim3 gs((NN + TPB_C - 1) / TPB_C, BB);                // 8 x 64
        stats_kernel<<<gs, TPB_C, 0, stream>>>(logits, stats);
        dim3 gf(MM, BB);                                      // 128 x 64
        fill_kernel<<<gf, 256, 0, stream>>>(boxes, tlabels, tboxes, stats, logits, costT);
    } else {
        dim3 g1((NN + TPB_C - 1) / TPB_C, BB);
        cost_kernel<<<g1, TPB_C, 0, stream>>>(logits, boxes, tlabels, tboxes, costT);
    }
    lsa_kernel<<<BB, 64, 0, stream>>>(costT, out);
}

// Round 11
// 402.082 us; speedup vs baseline: 1.0876x; 1.0876x over previous
//
#include <hip/hip_runtime.h>
#include <hip/hip_bf16.h>
#include <float.h>

#define BB 64
#define NN 900
#define CC 91
#define MM 128
#define BIG 1e18
#define DINF __builtin_huge_val()
#define NSLOT 15              // 15*64 = 960 >= 900 columns per lane-slot grid
#define LAST_VALID 4          // slot 14 valid for lanes 0..3 (896+lane < 900)
#define TPB_C 128

// ---------------------------------------------------------------------------
// Kernel 1a: per-pred softmax stats (mx, ssum), sequential reduction order
// identical to the passing cost_kernel. Writes float2 [mx,ssum] per pred.
// ---------------------------------------------------------------------------
__global__ __launch_bounds__(TPB_C) void stats_kernel(
    const float* __restrict__ logits,   // [B,N,C]
    float* __restrict__ stats)          // [B,N,2]
{
    const int b   = blockIdx.y;
    const int p0  = blockIdx.x * TPB_C;
    const int cnt = min(TPB_C, NN - p0);
    const int tid = threadIdx.x;

    __shared__ float s_lg[TPB_C * CC];   // 46592 B

    {
        const float* gbase = logits + ((size_t)b * NN + p0) * CC;
        const int total = cnt * CC;
        const int n4 = total >> 2;
        for (int k = tid; k < n4; k += TPB_C)
            ((float4*)s_lg)[k] = ((const float4*)gbase)[k];
        for (int k = (n4 << 2) + tid; k < total; k += TPB_C)
            s_lg[k] = gbase[k];
    }
    __syncthreads();
    if (tid >= cnt) return;

    const float* lg = s_lg + tid * CC;
    float mx = -INFINITY;
    for (int c = 0; c < CC; ++c) mx = fmaxf(mx, lg[c]);
    float ssum = 0.f;
    for (int c = 0; c < CC; ++c) ssum += expf(lg[c] - mx);

    ((float2*)stats)[(size_t)b * NN + p0 + tid] = make_float2(mx, ssum);
}

// ---------------------------------------------------------------------------
// Kernel 1b: cost fill. One block per (b, j) target pair; thread t computes
// 4 adjacent preds -> one coalesced float4 store. Expression tree identical
// to the passing cost_kernel.
// ---------------------------------------------------------------------------
__global__ __launch_bounds__(256) void fill_kernel(
    const float* __restrict__ boxes,    // [B,N,4]
    const int*   __restrict__ tlabels,  // [B,M]
    const float* __restrict__ tboxes,   // [B,M,4]
    const float* __restrict__ stats,    // [B,N,2]
    const float* __restrict__ logits,   // [B,N,C]
    float* __restrict__ costT)          // [B,M,N]
{
    const int j = blockIdx.x;           // target index
    const int b = blockIdx.y;
    const int t = threadIdx.x;
    if (t >= NN / 4) return;            // 225 active threads
    const int p4 = t * 4;

    const int    tl = tlabels[b * MM + j];
    const float4 tb = ((const float4*)tboxes)[(size_t)b * MM + j];
    const float tcx = tb.x, tcy = tb.y, tw = tb.z, th = tb.w;
    const float tx0 = tcx - 0.5f * tw, ty0 = tcy - 0.5f * th;
    const float tx1 = tcx + 0.5f * tw, ty1 = tcy + 0.5f * th;
    const float tarea = (tx1 - tx0) * (ty1 - ty0);

    const float4* bx4 = (const float4*)boxes + (size_t)b * NN + p4;
    const float4  s01 = ((const float4*)stats)[((size_t)b * NN + p4) >> 1];
    const float4  s23 = ((const float4*)stats)[(((size_t)b * NN + p4) >> 1) + 1];
    const float   smx[4] = {s01.x, s01.z, s23.x, s23.z};
    const float   ssm[4] = {s01.y, s01.w, s23.y, s23.w};

    float res[4];
    #pragma unroll
    for (int k = 0; k < 4; ++k) {
        const float4 bx = bx4[k];
        const float cx = bx.x, cy = bx.y, w = bx.z, h = bx.w;
        const float px0 = cx - 0.5f * w, py0 = cy - 0.5f * h;
        const float px1 = cx + 0.5f * w, py1 = cy + 0.5f * h;
        const float parea = (px1 - px0) * (py1 - py0);

        float l1 = ((fabsf(cx - tcx) + fabsf(cy - tcy)) + fabsf(w - tw)) + fabsf(h - th);
        float iw = fminf(px1, tx1) - fmaxf(px0, tx0); iw = fmaxf(iw, 0.f);
        float ih = fminf(py1, ty1) - fmaxf(py0, ty0); ih = fmaxf(ih, 0.f);
        const float inter = iw * ih;
        const float uni   = parea + tarea - inter;
        const float iou   = inter / (uni + 1e-6f);
        const float enc   = (fmaxf(px1, tx1) - fminf(px0, tx0)) *
                            (fmaxf(py1, ty1) - fminf(py0, ty0)) + 1e-6f;
        const float giou  = iou - (enc - uni) / enc;

        const float lgt  = logits[((size_t)b * NN + p4 + k) * CC + tl];
        const float pcls = expf(lgt - smx[k]) / ssm[k];
        res[k] = (1.0f * (-pcls) + 5.0f * l1) + 2.0f * (-giou);
    }
    ((float4*)(costT + (size_t)(b * MM + j) * NN))[t] =
        make_float4(res[0], res[1], res[2], res[3]);
}

// ---------------------------------------------------------------------------
// Fallback: round-3 monolithic cost kernel (used only if ws too small).
// ---------------------------------------------------------------------------
__global__ __launch_bounds__(TPB_C) void cost_kernel(
    const float* __restrict__ logits, const float* __restrict__ boxes,
    const int* __restrict__ tlabels, const float* __restrict__ tboxes,
    float* __restrict__ costT)
{
    const int b   = blockIdx.y;
    const int p0  = blockIdx.x * TPB_C;
    const int cnt = min(TPB_C, NN - p0);
    const int tid = threadIdx.x;

    __shared__ float s_lg[TPB_C * CC];
    __shared__ float s_tb[MM][4];
    __shared__ int   s_tl[MM];

    {
        s_tl[tid] = tlabels[b * MM + tid];
        const float4 tb4 = ((const float4*)tboxes)[(size_t)b * MM + tid];
        s_tb[tid][0] = tb4.x; s_tb[tid][1] = tb4.y;
        s_tb[tid][2] = tb4.z; s_tb[tid][3] = tb4.w;
    }
    {
        const float* gbase = logits + ((size_t)b * NN + p0) * CC;
        const int total = cnt * CC;
        const int n4 = total >> 2;
        for (int k = tid; k < n4; k += TPB_C)
            ((float4*)s_lg)[k] = ((const float4*)gbase)[k];
        for (int k = (n4 << 2) + tid; k < total; k += TPB_C)
            s_lg[k] = gbase[k];
    }
    __syncthreads();
    if (tid >= cnt) return;

    const float* lg = s_lg + tid * CC;
    float mx = -INFINITY;
    for (int c = 0; c < CC; ++c) mx = fmaxf(mx, lg[c]);
    float ssum = 0.f;
    for (int c = 0; c < CC; ++c) ssum += expf(lg[c] - mx);

    const float4 bx4 = ((const float4*)boxes)[(size_t)b * NN + p0 + tid];
    const float cx = bx4.x, cy = bx4.y, w = bx4.z, h = bx4.w;
    const float px0 = cx - 0.5f * w, py0 = cy - 0.5f * h;
    const float px1 = cx + 0.5f * w, py1 = cy + 0.5f * h;
    const float parea = (px1 - px0) * (py1 - py0);

    float* outp = costT + (size_t)b * MM * NN + p0 + tid;
    for (int j = 0; j < MM; ++j) {
        const float tcx = s_tb[j][0], tcy = s_tb[j][1], tw = s_tb[j][2], th = s_tb[j][3];
        float l1 = ((fabsf(cx - tcx) + fabsf(cy - tcy)) + fabsf(w - tw)) + fabsf(h - th);
        const float tx0 = tcx - 0.5f * tw, ty0 = tcy - 0.5f * th;
        const float tx1 = tcx + 0.5f * tw, ty1 = tcy + 0.5f * th;
        float iw = fminf(px1, tx1) - fmaxf(px0, tx0); iw = fmaxf(iw, 0.f);
        float ih = fminf(py1, ty1) - fmaxf(py0, ty0); ih = fmaxf(ih, 0.f);
        const float inter = iw * ih;
        const float tarea = (tx1 - tx0) * (ty1 - ty0);
        const float uni   = parea + tarea - inter;
        const float iou   = inter / (uni + 1e-6f);
        const float enc   = (fmaxf(px1, tx1) - fminf(px0, tx0)) *
                            (fmaxf(py1, ty1) - fminf(py0, ty0)) + 1e-6f;
        const float giou  = iou - (enc - uni) / enc;
        const float pcls  = expf(lg[s_tl[j]] - mx) / ssum;
        const float cost  = (1.0f * (-pcls) + 5.0f * l1) + 2.0f * (-giou);
        outp[(size_t)j * NN] = cost;
    }
}

// ---------------------------------------------------------------------------
// DPP helpers (literal-constant template args; min lands in lane 63).
// ---------------------------------------------------------------------------
template<int CTRL, int ROW_MASK>
__device__ __forceinline__ unsigned dpp_min_u32_step(unsigned x) {
    const unsigned m = (unsigned)__builtin_amdgcn_update_dpp((int)x, (int)x, CTRL, ROW_MASK, 0xF, false);
    return m < x ? m : x;
}
__device__ __forceinline__ unsigned wave_min_u32(unsigned x) {
    x = dpp_min_u32_step<0xB1,  0xF>(x);  // quad_perm xor1
    x = dpp_min_u32_step<0x4E,  0xF>(x);  // quad_perm xor2
    x = dpp_min_u32_step<0x141, 0xF>(x);  // row_half_mirror
    x = dpp_min_u32_step<0x140, 0xF>(x);  // row_mirror
    x = dpp_min_u32_step<0x142, 0xA>(x);  // row_bcast15 -> rows 1,3
    x = dpp_min_u32_step<0x143, 0xC>(x);  // row_bcast31 -> rows 2,3
    return (unsigned)__builtin_amdgcn_readlane((int)x, 63);
}
__device__ __forceinline__ int d_hi(double d) { return (int)(__double_as_longlong(d) >> 32); }
__device__ __forceinline__ int d_lo(double d) { return (int)__double_as_longlong(d); }
__device__ __forceinline__ double mk_d(int hi, int lo) {
    return __longlong_as_double(((long long)hi << 32) | (unsigned long long)(unsigned)lo);
}

// ---------------------------------------------------------------------------
// Kernel 2: JV LSA, one wave per batch. Round-11 (f64-issue trims vs r9):
//  - minv pinned to +INF ONCE at marking (scalar branch on uniform slot id);
//    per-iteration minv update is now an UNCONDITIONAL f64 sub (INF-d=INF)
//  - v update via operand select: v -= (ub ? delta : 0.0); exact since
//    x - 0.0 == x bitwise for all x (incl -0.0 - 0.0 = -0.0)
//  - row loads via lane-folded base + imm offsets (s*256 <= 3584)
// Reference f64 op order / rounding / argmin tie-breaks preserved exactly.
// ---------------------------------------------------------------------------
__global__ __launch_bounds__(64) void lsa_kernel(
    const float* __restrict__ costT,  // [B,M,N]
    int* __restrict__ out)            // rows [B,M] then cols [B,M], int32
{
    const int b    = blockIdx.x;
    const int lane = threadIdx.x;

    __shared__ double s_u[MM + 1];
    __shared__ int    s_p[NN + 1];
    __shared__ int    s_c4r[MM];
    __shared__ int    s_spill[3 * (NN + 2)];   // pathological path spill

    double v[NSLOT], minv[NSLOT];
    unsigned pay[NSLOT], pay_base[NSLOT];
    float  cv[NSLOT];

    for (int j = lane; j <= NN; j += 64) s_p[j] = 0;
    for (int i = lane; i <= MM; i += 64) s_u[i] = 0.0;
    #pragma unroll
    for (int s = 0; s < NSLOT; ++s) {
        v[s] = 0.0;
        pay_base[s] = ((unsigned)(s * 64 + lane + 1) << 18);  // p=0 initially
        pay[s] = pay_base[s];
    }
    __syncthreads();

    const float* cb = costT + (size_t)b * MM * NN;

    // prefetch row 0 (Dijkstra i=1), lane-folded base + imm offsets
    {
        const float* crow_l = cb + lane;
        #pragma unroll
        for (int s = 0; s < NSLOT - 1; ++s) cv[s] = crow_l[s * 64];
        cv[NSLOT - 1] = (lane < LAST_VALID) ? crow_l[(NSLOT - 1) * 64] : 0.f;
    }

    for (int i = 1; i <= MM; ++i) {
        unsigned used_mask = 0;
        #pragma unroll
        for (int s = 0; s < NSLOT; ++s) minv[s] = BIG;

        int T = 0;
        int curj0 = 0;
        int curi0 = i;
        int curway = 0;
        int nspill = 0;
        double ui0 = 0.0;   // u[i]==0: fresh row never touched before
        int my_j0 = -1, my_i0 = 0, my_way = 0;

        while (true) {
            if (T < 63) {
                if (lane == T) { my_j0 = curj0; my_i0 = curi0; my_way = curway; }
            } else {
                if (lane == 0) {
                    s_spill[3 * nspill]     = curj0;
                    s_spill[3 * nspill + 1] = curi0;
                    s_spill[3 * nspill + 2] = curway;
                }
                ++nspill;
            }
            // mark curj0 used + pin its minv to +INF (once; slot id is uniform)
            if (curj0 > 0) {
                const int jp   = curj0 - 1;
                const int slot = jp >> 6;
                const int tgt  = jp & 63;
                if (tgt == lane) used_mask |= 1u << slot;
                #pragma unroll
                for (int s = 0; s < NSLOT; ++s)
                    if (slot == s) minv[s] = (lane == tgt) ? DINF : minv[s];
            }

            // ---- scan: fr-guarded improvement of (minv, payload)
            const unsigned pay_or = (unsigned)curj0 << 8;
            #pragma unroll
            for (int s = 0; s < NSLOT; ++s) {
                const bool valid = (s < NSLOT - 1) || (lane < LAST_VALID);
                const bool fr = valid && !((used_mask >> s) & 1u);
                const double cur = ((double)cv[s] - ui0) - v[s];
                const bool imp = fr && (cur < minv[s]);
                if (imp) { minv[s] = cur; pay[s] = pay_base[s] | pay_or; }
            }

            // ---- per-lane tournament tree (depth 4), left wins ties
            double n1v[8]; unsigned n1p[8];
            #pragma unroll
            for (int s = 0; s < 8; ++s) {
                const int a = 2 * s, c = 2 * s + 1;
                double va = minv[a]; unsigned pa = pay[a];
                if (c < NSLOT) { if (minv[c] < va) { va = minv[c]; pa = pay[c]; } }
                n1v[s] = va; n1p[s] = pa;
            }
            double n2v[4]; unsigned n2p[4];
            #pragma unroll
            for (int s = 0; s < 4; ++s) {
                double va = n1v[2*s]; unsigned pa = n1p[2*s];
                if (n1v[2*s+1] < va) { va = n1v[2*s+1]; pa = n1p[2*s+1]; }
                n2v[s] = va; n2p[s] = pa;
            }
            double n3v[2]; unsigned n3p[2];
            #pragma unroll
            for (int s = 0; s < 2; ++s) {
                double va = n2v[2*s]; unsigned pa = n2p[2*s];
                if (n2v[2*s+1] < va) { va = n2v[2*s+1]; pa = n2p[2*s+1]; }
                n3v[s] = va; n3p[s] = pa;
            }
            double bv = n3v[0]; unsigned bpay = n3p[0];
            if (n3v[1] < bv) { bv = n3v[1]; bpay = n3p[1]; }

            // ---- cross-lane argmin: hi-word DPP fast path
            const double bvn = bv + 0.0;
            const int hi = d_hi(bvn);
            const int sm = hi >> 31;
            const unsigned th = (unsigned)(hi ^ (sm | 0x80000000));
            const unsigned minhi = wave_min_u32(th);

            const unsigned long long hit = __ballot(th == minhi);
            unsigned wpay; double delta;
            if (__builtin_popcountll(hit) == 1) {
                const int src = (int)__builtin_ctzll(hit);
                wpay  = (unsigned)__builtin_amdgcn_readlane((int)bpay, src);
                delta = mk_d(__builtin_amdgcn_readlane(hi, src),
                             __builtin_amdgcn_readlane(d_lo(bvn), src));
            } else {
                const unsigned tl = (unsigned)(d_lo(bvn) ^ sm);
                const unsigned minlo = wave_min_u32((th == minhi) ? tl : 0xFFFFFFFFu);
                const bool full = (th == minhi) && (tl == minlo);
                wpay = wave_min_u32(full ? bpay : 0xFFFFFFFFu);
                const int src = (int)__builtin_ctzll(__ballot(full));
                delta = mk_d(__builtin_amdgcn_readlane(hi, src),
                             __builtin_amdgcn_readlane(d_lo(bvn), src));
            }
            const int j1   = (int)(wpay >> 18);
            const int way1 = (int)((wpay >> 8) & 0x3FF);
            const int pj1  = (int)(wpay & 0xFF);

            // issue next-row loads ASAP (lane-folded base + imm offsets)
            double ui_next = 0.0;
            if (pj1 != 0) {
                const float* crow_l = cb + (size_t)(pj1 - 1) * NN + lane;
                #pragma unroll
                for (int s = 0; s < NSLOT - 1; ++s) cv[s] = crow_l[s * 64];
                if (lane < LAST_VALID) cv[NSLOT - 1] = crow_l[(NSLOT - 1) * 64];
                ui_next = s_u[pj1];
            }

            // ---- u-updates (rows of used columns distinct -> parallel RMW)
            if (T < 63) {
                if (lane <= T) s_u[my_i0] += delta;
            } else {
                if (lane == 0) s_u[i] += delta;
                double uval[NSLOT];
                #pragma unroll
                for (int s = 0; s < NSLOT; ++s) {
                    const bool valid = (s < NSLOT - 1) || (lane < LAST_VALID);
                    if (valid && ((used_mask >> s) & 1u))
                        uval[s] = s_u[pay_base[s] & 0xFF];
                }
                #pragma unroll
                for (int s = 0; s < NSLOT; ++s) {
                    const bool valid = (s < NSLOT - 1) || (lane < LAST_VALID);
                    if (valid && ((used_mask >> s) & 1u))
                        s_u[pay_base[s] & 0xFF] = uval[s] + delta;
                }
            }
            // ---- v / minv updates:
            //  v    -= (ub ? delta : 0.0)   (x-0.0 == x bitwise, incl -0.0)
            //  minv -= delta unconditionally (used slots pinned +INF; INF-d=INF;
            //  invalid slot-14 lanes drift from BIG harmlessly, fr-guard blocks)
            #pragma unroll
            for (int s = 0; s < NSLOT; ++s) {
                const bool ub = (used_mask >> s) & 1u;
                const double dv = ub ? delta : 0.0;
                v[s]    -= dv;
                minv[s] -= delta;
            }

            if (pj1 == 0) {
                // ---- augment via register chase
                int ja = j1, jb = way1;
                const int cap = (T < 63) ? T : 62;
                while (jb != 0) {
                    int np, nw;
                    const unsigned long long bal = __ballot(lane <= cap && my_j0 == jb);
                    if (bal != 0) {
                        const int src = (int)__builtin_ctzll(bal);
                        np = __builtin_amdgcn_readlane(my_i0, src);
                        nw = __builtin_amdgcn_readlane(my_way, src);
                    } else {
                        np = 0; nw = 0;
                        for (int k = 0; k < nspill; ++k) {
                            if (s_spill[3 * k] == jb) {
                                np = s_spill[3 * k + 1];
                                nw = s_spill[3 * k + 2];
                                break;
                            }
                        }
                    }
                    if (lane == 0) s_p[ja] = np;
                    ja = jb; jb = nw;
                }
                if (lane == 0) s_p[ja] = i;
                break;
            }
            curj0 = j1; curi0 = pj1; curway = way1; ui0 = ui_next; ++T;
        }

        // refresh cached p[j] (payload base) for this lane's columns
        #pragma unroll
        for (int s = 0; s < NSLOT; ++s) {
            const bool valid = (s < NSLOT - 1) || (lane < LAST_VALID);
            if (valid) {
                const int j = s * 64 + lane + 1;
                pay_base[s] = ((unsigned)j << 18) | (unsigned)s_p[j];
            }
        }
        // prefetch first row of next Dijkstra (cost row index = i, 0-based)
        if (i < MM) {
            const float* crow_l = cb + (size_t)i * NN + lane;
            #pragma unroll
            for (int s = 0; s < NSLOT - 1; ++s) cv[s] = crow_l[s * 64];
            if (lane < LAST_VALID) cv[NSLOT - 1] = crow_l[(NSLOT - 1) * 64];
        }
    }

    // col4row: target t -> matched pred index
    for (int j = 1 + lane; j <= NN; j += 64) {
        const int pj = s_p[j];
        if (pj > 0) s_c4r[pj - 1] = j - 1;
    }
    __syncthreads();

    // transposed return: rows = sorted pred indices, cols = target permutation
    for (int t = lane; t < MM; t += 64) {
        const int val = s_c4r[t];
        int rank = 0;
        for (int q = 0; q < MM; ++q) rank += (s_c4r[q] < val);
        out[(size_t)b * MM + rank] = val;
        out[(size_t)BB * MM + (size_t)b * MM + rank] = t;
    }
}

extern "C" void kernel_launch(void* const* d_in, const int* in_sizes, int n_in,
                              void* d_out, int out_size, void* d_ws, size_t ws_size,
                              hipStream_t stream) {
    const float* logits  = (const float*)d_in[0];   // [64,900,91] f32
    const float* boxes   = (const float*)d_in[1];   // [64,900,4]  f32
    const int*   tlabels = (const int*)d_in[2];     // [64,128]    i32 (from i64)
    const float* tboxes  = (const float*)d_in[3];   // [64,128,4]  f32
    int*   out   = (int*)d_out;                     // rows[64,128] ++ cols[64,128]
    float* costT = (float*)d_ws;                    // [64,128,900] f32

    const size_t costT_bytes = (size_t)BB * MM * NN * 4;
    const size_t stats_bytes = (size_t)BB * NN * 2 * 4;

    if (ws_size >= costT_bytes + stats_bytes) {
        float* stats = (float*)((char*)d_ws + costT_bytes);   // [64,900,2]
        dim3 gs((NN + TPB_C - 1) / TPB_C, BB);                // 8 x 64
        stats_kernel<<<gs, TPB_C, 0, stream>>>(logits, stats);
        dim3 gf(MM, BB);                                      // 128 x 64
        fill_kernel<<<gf, 256, 0, stream>>>(boxes, tlabels, tboxes, stats, logits, costT);
    } else {
        dim3 g1((NN + TPB_C - 1) / TPB_C, BB);
        cost_kernel<<<g1, TPB_C, 0, stream>>>(logits, boxes, tlabels, tboxes, costT);
    }
    lsa_kernel<<<BB, 64, 0, stream>>>(costT, out);
}

// Round 12
// 397.031 us; speedup vs baseline: 1.1014x; 1.0127x over previous
//
#include <hip/hip_runtime.h>
#include <hip/hip_bf16.h>
#include <float.h>

#define BB 64
#define NN 900
#define CC 91
#define MM 128
#define BIG 1e18
#define DINF __builtin_huge_val()
#define NSLOT 15              // 15*64 = 960 >= 900 columns per lane-slot grid
#define LAST_VALID 4          // slot 14 valid for lanes 0..3 (896+lane < 900)
#define TPB_C 128

// ---------------------------------------------------------------------------
// Kernel 1a: per-pred softmax stats (mx, ssum), sequential reduction order
// identical to the passing cost_kernel. Writes float2 [mx,ssum] per pred.
// ---------------------------------------------------------------------------
__global__ __launch_bounds__(TPB_C) void stats_kernel(
    const float* __restrict__ logits,   // [B,N,C]
    float* __restrict__ stats)          // [B,N,2]
{
    const int b   = blockIdx.y;
    const int p0  = blockIdx.x * TPB_C;
    const int cnt = min(TPB_C, NN - p0);
    const int tid = threadIdx.x;

    __shared__ float s_lg[TPB_C * CC];   // 46592 B

    {
        const float* gbase = logits + ((size_t)b * NN + p0) * CC;
        const int total = cnt * CC;
        const int n4 = total >> 2;
        for (int k = tid; k < n4; k += TPB_C)
            ((float4*)s_lg)[k] = ((const float4*)gbase)[k];
        for (int k = (n4 << 2) + tid; k < total; k += TPB_C)
            s_lg[k] = gbase[k];
    }
    __syncthreads();
    if (tid >= cnt) return;

    const float* lg = s_lg + tid * CC;
    float mx = -INFINITY;
    for (int c = 0; c < CC; ++c) mx = fmaxf(mx, lg[c]);
    float ssum = 0.f;
    for (int c = 0; c < CC; ++c) ssum += expf(lg[c] - mx);

    ((float2*)stats)[(size_t)b * NN + p0 + tid] = make_float2(mx, ssum);
}

// ---------------------------------------------------------------------------
// Kernel 1b: cost fill. Round-12: grid is BATCH-MAJOR (b = blockIdx.x) so
// all blocks of batch b land on XCD b%8 (flat-id %8 heuristic) — the same
// XCD as lsa block b. costT writes then populate the LOCAL L2, turning lsa's
// first-touch row reads from HBM (~900cy) into local-L2 hits (~200cy).
// Expression tree identical to the passing cost_kernel.
// ---------------------------------------------------------------------------
__global__ __launch_bounds__(256) void fill_kernel(
    const float* __restrict__ boxes,    // [B,N,4]
    const int*   __restrict__ tlabels,  // [B,M]
    const float* __restrict__ tboxes,   // [B,M,4]
    const float* __restrict__ stats,    // [B,N,2]
    const float* __restrict__ logits,   // [B,N,C]
    float* __restrict__ costT)          // [B,M,N]
{
    const int b = blockIdx.x;           // batch-major: flat id % 8 == b % 8
    const int j = blockIdx.y;           // target index
    const int t = threadIdx.x;
    if (t >= NN / 4) return;            // 225 active threads
    const int p4 = t * 4;

    const int    tl = tlabels[b * MM + j];
    const float4 tb = ((const float4*)tboxes)[(size_t)b * MM + j];
    const float tcx = tb.x, tcy = tb.y, tw = tb.z, th = tb.w;
    const float tx0 = tcx - 0.5f * tw, ty0 = tcy - 0.5f * th;
    const float tx1 = tcx + 0.5f * tw, ty1 = tcy + 0.5f * th;
    const float tarea = (tx1 - tx0) * (ty1 - ty0);

    const float4* bx4 = (const float4*)boxes + (size_t)b * NN + p4;
    const float4  s01 = ((const float4*)stats)[((size_t)b * NN + p4) >> 1];
    const float4  s23 = ((const float4*)stats)[(((size_t)b * NN + p4) >> 1) + 1];
    const float   smx[4] = {s01.x, s01.z, s23.x, s23.z};
    const float   ssm[4] = {s01.y, s01.w, s23.y, s23.w};

    float res[4];
    #pragma unroll
    for (int k = 0; k < 4; ++k) {
        const float4 bx = bx4[k];
        const float cx = bx.x, cy = bx.y, w = bx.z, h = bx.w;
        const float px0 = cx - 0.5f * w, py0 = cy - 0.5f * h;
        const float px1 = cx + 0.5f * w, py1 = cy + 0.5f * h;
        const float parea = (px1 - px0) * (py1 - py0);

        float l1 = ((fabsf(cx - tcx) + fabsf(cy - tcy)) + fabsf(w - tw)) + fabsf(h - th);
        float iw = fminf(px1, tx1) - fmaxf(px0, tx0); iw = fmaxf(iw, 0.f);
        float ih = fminf(py1, ty1) - fmaxf(py0, ty0); ih = fmaxf(ih, 0.f);
        const float inter = iw * ih;
        const float uni   = parea + tarea - inter;
        const float iou   = inter / (uni + 1e-6f);
        const float enc   = (fmaxf(px1, tx1) - fminf(px0, tx0)) *
                            (fmaxf(py1, ty1) - fminf(py0, ty0)) + 1e-6f;
        const float giou  = iou - (enc - uni) / enc;

        const float lgt  = logits[((size_t)b * NN + p4 + k) * CC + tl];
        const float pcls = expf(lgt - smx[k]) / ssm[k];
        res[k] = (1.0f * (-pcls) + 5.0f * l1) + 2.0f * (-giou);
    }
    ((float4*)(costT + (size_t)(b * MM + j) * NN))[t] =
        make_float4(res[0], res[1], res[2], res[3]);
}

// ---------------------------------------------------------------------------
// Fallback: round-3 monolithic cost kernel (used only if ws too small).
// ---------------------------------------------------------------------------
__global__ __launch_bounds__(TPB_C) void cost_kernel(
    const float* __restrict__ logits, const float* __restrict__ boxes,
    const int* __restrict__ tlabels, const float* __restrict__ tboxes,
    float* __restrict__ costT)
{
    const int b   = blockIdx.y;
    const int p0  = blockIdx.x * TPB_C;
    const int cnt = min(TPB_C, NN - p0);
    const int tid = threadIdx.x;

    __shared__ float s_lg[TPB_C * CC];
    __shared__ float s_tb[MM][4];
    __shared__ int   s_tl[MM];

    {
        s_tl[tid] = tlabels[b * MM + tid];
        const float4 tb4 = ((const float4*)tboxes)[(size_t)b * MM + tid];
        s_tb[tid][0] = tb4.x; s_tb[tid][1] = tb4.y;
        s_tb[tid][2] = tb4.z; s_tb[tid][3] = tb4.w;
    }
    {
        const float* gbase = logits + ((size_t)b * NN + p0) * CC;
        const int total = cnt * CC;
        const int n4 = total >> 2;
        for (int k = tid; k < n4; k += TPB_C)
            ((float4*)s_lg)[k] = ((const float4*)gbase)[k];
        for (int k = (n4 << 2) + tid; k < total; k += TPB_C)
            s_lg[k] = gbase[k];
    }
    __syncthreads();
    if (tid >= cnt) return;

    const float* lg = s_lg + tid * CC;
    float mx = -INFINITY;
    for (int c = 0; c < CC; ++c) mx = fmaxf(mx, lg[c]);
    float ssum = 0.f;
    for (int c = 0; c < CC; ++c) ssum += expf(lg[c] - mx);

    const float4 bx4 = ((const float4*)boxes)[(size_t)b * NN + p0 + tid];
    const float cx = bx4.x, cy = bx4.y, w = bx4.z, h = bx4.w;
    const float px0 = cx - 0.5f * w, py0 = cy - 0.5f * h;
    const float px1 = cx + 0.5f * w, py1 = cy + 0.5f * h;
    const float parea = (px1 - px0) * (py1 - py0);

    float* outp = costT + (size_t)b * MM * NN + p0 + tid;
    for (int j = 0; j < MM; ++j) {
        const float tcx = s_tb[j][0], tcy = s_tb[j][1], tw = s_tb[j][2], th = s_tb[j][3];
        float l1 = ((fabsf(cx - tcx) + fabsf(cy - tcy)) + fabsf(w - tw)) + fabsf(h - th);
        const float tx0 = tcx - 0.5f * tw, ty0 = tcy - 0.5f * th;
        const float tx1 = tcx + 0.5f * tw, ty1 = tcy + 0.5f * th;
        float iw = fminf(px1, tx1) - fmaxf(px0, tx0); iw = fmaxf(iw, 0.f);
        float ih = fminf(py1, ty1) - fmaxf(py0, ty0); ih = fmaxf(ih, 0.f);
        const float inter = iw * ih;
        const float tarea = (tx1 - tx0) * (ty1 - ty0);
        const float uni   = parea + tarea - inter;
        const float iou   = inter / (uni + 1e-6f);
        const float enc   = (fmaxf(px1, tx1) - fminf(px0, tx0)) *
                            (fmaxf(py1, ty1) - fminf(py0, ty0)) + 1e-6f;
        const float giou  = iou - (enc - uni) / enc;
        const float pcls  = expf(lg[s_tl[j]] - mx) / ssum;
        const float cost  = (1.0f * (-pcls) + 5.0f * l1) + 2.0f * (-giou);
        outp[(size_t)j * NN] = cost;
    }
}

// ---------------------------------------------------------------------------
// DPP helpers (literal-constant template args; min lands in lane 63).
// ---------------------------------------------------------------------------
template<int CTRL, int ROW_MASK>
__device__ __forceinline__ unsigned dpp_min_u32_step(unsigned x) {
    const unsigned m = (unsigned)__builtin_amdgcn_update_dpp((int)x, (int)x, CTRL, ROW_MASK, 0xF, false);
    return m < x ? m : x;
}
__device__ __forceinline__ unsigned wave_min_u32(unsigned x) {
    x = dpp_min_u32_step<0xB1,  0xF>(x);  // quad_perm xor1
    x = dpp_min_u32_step<0x4E,  0xF>(x);  // quad_perm xor2
    x = dpp_min_u32_step<0x141, 0xF>(x);  // row_half_mirror
    x = dpp_min_u32_step<0x140, 0xF>(x);  // row_mirror
    x = dpp_min_u32_step<0x142, 0xA>(x);  // row_bcast15 -> rows 1,3
    x = dpp_min_u32_step<0x143, 0xC>(x);  // row_bcast31 -> rows 2,3
    return (unsigned)__builtin_amdgcn_readlane((int)x, 63);
}
__device__ __forceinline__ int d_hi(double d) { return (int)(__double_as_longlong(d) >> 32); }
__device__ __forceinline__ int d_lo(double d) { return (int)__double_as_longlong(d); }
__device__ __forceinline__ double mk_d(int hi, int lo) {
    return __longlong_as_double(((long long)hi << 32) | (unsigned long long)(unsigned)lo);
}

// ---------------------------------------------------------------------------
// Kernel 2: JV LSA, one wave per batch. UNCHANGED from round-11 (276 us,
// absmax 0) to isolate the XCD-locality experiment.
// ---------------------------------------------------------------------------
__global__ __launch_bounds__(64) void lsa_kernel(
    const float* __restrict__ costT,  // [B,M,N]
    int* __restrict__ out)            // rows [B,M] then cols [B,M], int32
{
    const int b    = blockIdx.x;
    const int lane = threadIdx.x;

    __shared__ double s_u[MM + 1];
    __shared__ int    s_p[NN + 1];
    __shared__ int    s_c4r[MM];
    __shared__ int    s_spill[3 * (NN + 2)];   // pathological path spill

    double v[NSLOT], minv[NSLOT];
    unsigned pay[NSLOT], pay_base[NSLOT];
    float  cv[NSLOT];

    for (int j = lane; j <= NN; j += 64) s_p[j] = 0;
    for (int i = lane; i <= MM; i += 64) s_u[i] = 0.0;
    #pragma unroll
    for (int s = 0; s < NSLOT; ++s) {
        v[s] = 0.0;
        pay_base[s] = ((unsigned)(s * 64 + lane + 1) << 18);  // p=0 initially
        pay[s] = pay_base[s];
    }
    __syncthreads();

    const float* cb = costT + (size_t)b * MM * NN;

    // prefetch row 0 (Dijkstra i=1), lane-folded base + imm offsets
    {
        const float* crow_l = cb + lane;
        #pragma unroll
        for (int s = 0; s < NSLOT - 1; ++s) cv[s] = crow_l[s * 64];
        cv[NSLOT - 1] = (lane < LAST_VALID) ? crow_l[(NSLOT - 1) * 64] : 0.f;
    }

    for (int i = 1; i <= MM; ++i) {
        unsigned used_mask = 0;
        #pragma unroll
        for (int s = 0; s < NSLOT; ++s) minv[s] = BIG;

        int T = 0;
        int curj0 = 0;
        int curi0 = i;
        int curway = 0;
        int nspill = 0;
        double ui0 = 0.0;   // u[i]==0: fresh row never touched before
        int my_j0 = -1, my_i0 = 0, my_way = 0;

        while (true) {
            if (T < 63) {
                if (lane == T) { my_j0 = curj0; my_i0 = curi0; my_way = curway; }
            } else {
                if (lane == 0) {
                    s_spill[3 * nspill]     = curj0;
                    s_spill[3 * nspill + 1] = curi0;
                    s_spill[3 * nspill + 2] = curway;
                }
                ++nspill;
            }
            // mark curj0 used + pin its minv to +INF (once; slot id is uniform)
            if (curj0 > 0) {
                const int jp   = curj0 - 1;
                const int slot = jp >> 6;
                const int tgt  = jp & 63;
                if (tgt == lane) used_mask |= 1u << slot;
                #pragma unroll
                for (int s = 0; s < NSLOT; ++s)
                    if (slot == s) minv[s] = (lane == tgt) ? DINF : minv[s];
            }

            // ---- scan: fr-guarded improvement of (minv, payload)
            const unsigned pay_or = (unsigned)curj0 << 8;
            #pragma unroll
            for (int s = 0; s < NSLOT; ++s) {
                const bool valid = (s < NSLOT - 1) || (lane < LAST_VALID);
                const bool fr = valid && !((used_mask >> s) & 1u);
                const double cur = ((double)cv[s] - ui0) - v[s];
                const bool imp = fr && (cur < minv[s]);
                if (imp) { minv[s] = cur; pay[s] = pay_base[s] | pay_or; }
            }

            // ---- per-lane tournament tree (depth 4), left wins ties
            double n1v[8]; unsigned n1p[8];
            #pragma unroll
            for (int s = 0; s < 8; ++s) {
                const int a = 2 * s, c = 2 * s + 1;
                double va = minv[a]; unsigned pa = pay[a];
                if (c < NSLOT) { if (minv[c] < va) { va = minv[c]; pa = pay[c]; } }
                n1v[s] = va; n1p[s] = pa;
            }
            double n2v[4]; unsigned n2p[4];
            #pragma unroll
            for (int s = 0; s < 4; ++s) {
                double va = n1v[2*s]; unsigned pa = n1p[2*s];
                if (n1v[2*s+1] < va) { va = n1v[2*s+1]; pa = n1p[2*s+1]; }
                n2v[s] = va; n2p[s] = pa;
            }
            double n3v[2]; unsigned n3p[2];
            #pragma unroll
            for (int s = 0; s < 2; ++s) {
                double va = n2v[2*s]; unsigned pa = n2p[2*s];
                if (n2v[2*s+1] < va) { va = n2v[2*s+1]; pa = n2p[2*s+1]; }
                n3v[s] = va; n3p[s] = pa;
            }
            double bv = n3v[0]; unsigned bpay = n3p[0];
            if (n3v[1] < bv) { bv = n3v[1]; bpay = n3p[1]; }

            // ---- cross-lane argmin: hi-word DPP fast path
            const double bvn = bv + 0.0;
            const int hi = d_hi(bvn);
            const int sm = hi >> 31;
            const unsigned th = (unsigned)(hi ^ (sm | 0x80000000));
            const unsigned minhi = wave_min_u32(th);

            const unsigned long long hit = __ballot(th == minhi);
            unsigned wpay; double delta;
            if (__builtin_popcountll(hit) == 1) {
                const int src = (int)__builtin_ctzll(hit);
                wpay  = (unsigned)__builtin_amdgcn_readlane((int)bpay, src);
                delta = mk_d(__builtin_amdgcn_readlane(hi, src),
                             __builtin_amdgcn_readlane(d_lo(bvn), src));
            } else {
                const unsigned tl = (unsigned)(d_lo(bvn) ^ sm);
                const unsigned minlo = wave_min_u32((th == minhi) ? tl : 0xFFFFFFFFu);
                const bool full = (th == minhi) && (tl == minlo);
                wpay = wave_min_u32(full ? bpay : 0xFFFFFFFFu);
                const int src = (int)__builtin_ctzll(__ballot(full));
                delta = mk_d(__builtin_amdgcn_readlane(hi, src),
                             __builtin_amdgcn_readlane(d_lo(bvn), src));
            }
            const int j1   = (int)(wpay >> 18);
            const int way1 = (int)((wpay >> 8) & 0x3FF);
            const int pj1  = (int)(wpay & 0xFF);

            // issue next-row loads ASAP (lane-folded base + imm offsets)
            double ui_next = 0.0;
            if (pj1 != 0) {
                const float* crow_l = cb + (size_t)(pj1 - 1) * NN + lane;
                #pragma unroll
                for (int s = 0; s < NSLOT - 1; ++s) cv[s] = crow_l[s * 64];
                if (lane < LAST_VALID) cv[NSLOT - 1] = crow_l[(NSLOT - 1) * 64];
                ui_next = s_u[pj1];
            }

            // ---- u-updates (rows of used columns distinct -> parallel RMW)
            if (T < 63) {
                if (lane <= T) s_u[my_i0] += delta;
            } else {
                if (lane == 0) s_u[i] += delta;
                double uval[NSLOT];
                #pragma unroll
                for (int s = 0; s < NSLOT; ++s) {
                    const bool valid = (s < NSLOT - 1) || (lane < LAST_VALID);
                    if (valid && ((used_mask >> s) & 1u))
                        uval[s] = s_u[pay_base[s] & 0xFF];
                }
                #pragma unroll
                for (int s = 0; s < NSLOT; ++s) {
                    const bool valid = (s < NSLOT - 1) || (lane < LAST_VALID);
                    if (valid && ((used_mask >> s) & 1u))
                        s_u[pay_base[s] & 0xFF] = uval[s] + delta;
                }
            }
            // ---- v / minv updates:
            //  v    -= (ub ? delta : 0.0)   (x-0.0 == x bitwise, incl -0.0)
            //  minv -= delta unconditionally (used slots pinned +INF)
            #pragma unroll
            for (int s = 0; s < NSLOT; ++s) {
                const bool ub = (used_mask >> s) & 1u;
                const double dv = ub ? delta : 0.0;
                v[s]    -= dv;
                minv[s] -= delta;
            }

            if (pj1 == 0) {
                // ---- augment via register chase
                int ja = j1, jb = way1;
                const int cap = (T < 63) ? T : 62;
                while (jb != 0) {
                    int np, nw;
                    const unsigned long long bal = __ballot(lane <= cap && my_j0 == jb);
                    if (bal != 0) {
                        const int src = (int)__builtin_ctzll(bal);
                        np = __builtin_amdgcn_readlane(my_i0, src);
                        nw = __builtin_amdgcn_readlane(my_way, src);
                    } else {
                        np = 0; nw = 0;
                        for (int k = 0; k < nspill; ++k) {
                            if (s_spill[3 * k] == jb) {
                                np = s_spill[3 * k + 1];
                                nw = s_spill[3 * k + 2];
                                break;
                            }
                        }
                    }
                    if (lane == 0) s_p[ja] = np;
                    ja = jb; jb = nw;
                }
                if (lane == 0) s_p[ja] = i;
                break;
            }
            curj0 = j1; curi0 = pj1; curway = way1; ui0 = ui_next; ++T;
        }

        // refresh cached p[j] (payload base) for this lane's columns
        #pragma unroll
        for (int s = 0; s < NSLOT; ++s) {
            const bool valid = (s < NSLOT - 1) || (lane < LAST_VALID);
            if (valid) {
                const int j = s * 64 + lane + 1;
                pay_base[s] = ((unsigned)j << 18) | (unsigned)s_p[j];
            }
        }
        // prefetch first row of next Dijkstra (cost row index = i, 0-based)
        if (i < MM) {
            const float* crow_l = cb + (size_t)i * NN + lane;
            #pragma unroll
            for (int s = 0; s < NSLOT - 1; ++s) cv[s] = crow_l[s * 64];
            if (lane < LAST_VALID) cv[NSLOT - 1] = crow_l[(NSLOT - 1) * 64];
        }
    }

    // col4row: target t -> matched pred index
    for (int j = 1 + lane; j <= NN; j += 64) {
        const int pj = s_p[j];
        if (pj > 0) s_c4r[pj - 1] = j - 1;
    }
    __syncthreads();

    // transposed return: rows = sorted pred indices, cols = target permutation
    for (int t = lane; t < MM; t += 64) {
        const int val = s_c4r[t];
        int rank = 0;
        for (int q = 0; q < MM; ++q) rank += (s_c4r[q] < val);
        out[(size_t)b * MM + rank] = val;
        out[(size_t)BB * MM + (size_t)b * MM + rank] = t;
    }
}

extern "C" void kernel_launch(void* const* d_in, const int* in_sizes, int n_in,
                              void* d_out, int out_size, void* d_ws, size_t ws_size,
                              hipStream_t stream) {
    const float* logits  = (const float*)d_in[0];   // [64,900,91] f32
    const float* boxes   = (const float*)d_in[1];   // [64,900,4]  f32
    const int*   tlabels = (const int*)d_in[2];     // [64,128]    i32 (from i64)
    const float* tboxes  = (const float*)d_in[3];   // [64,128,4]  f32
    int*   out   = (int*)d_out;                     // rows[64,128] ++ cols[64,128]
    float* costT = (float*)d_ws;                    // [64,128,900] f32

    const size_t costT_bytes = (size_t)BB * MM * NN * 4;
    const size_t stats_bytes = (size_t)BB * NN * 2 * 4;

    if (ws_size >= costT_bytes + stats_bytes) {
        float* stats = (float*)((char*)d_ws + costT_bytes);   // [64,900,2]
        dim3 gs((NN + TPB_C - 1) / TPB_C, BB);                // 8 x 64
        stats_kernel<<<gs, TPB_C, 0, stream>>>(logits, stats);
        dim3 gf(BB, MM);                                      // batch-major: 64 x 128
        fill_kernel<<<gf, 256, 0, stream>>>(boxes, tlabels, tboxes, stats, logits, costT);
    } else {
        dim3 g1((NN + TPB_C - 1) / TPB_C, BB);
        cost_kernel<<<g1, TPB_C, 0, stream>>>(logits, boxes, tlabels, tboxes, costT);
    }
    lsa_kernel<<<BB, 64, 0, stream>>>(costT, out);
}